// Round 2
// baseline (2086.932 us; speedup 1.0000x reference)
//
#include <hip/hip_runtime.h>

#define T_LEN 2000
#define BATCH 32
#define ALPHA 1024
#define BLANK 0

typedef float f4 __attribute__((ext_vector_type(4)));

// Fused CTC greedy decode.
// Phase 1 (all waves): argmax over alphabet for one (t,b) row -> ml[b][t].
// Phase 2 (last-arriving wave per batch): sequential compaction, overlapped
// with the argmax tail via per-batch completion counters + device fences.
__global__ __launch_bounds__(256) void ctc_fused_kernel(
    const float* __restrict__ x, const int* __restrict__ lengths,
    int* __restrict__ out, int* __restrict__ ml, int* __restrict__ counters)
{
    const int wave = threadIdx.x >> 6;
    const int lane = threadIdx.x & 63;
    const int row  = blockIdx.x * 4 + wave;      // row = t*BATCH + b
    // grid is exact: 64000 rows / 4 waves per block -> no bounds check needed,
    // but keep it cheap and safe:
    if (row >= T_LEN * BATCH) return;

    // ---------------- Phase 1: argmax over 1024 floats ----------------
    const f4* rp = (const f4*)(x + (size_t)row * ALPHA);

    float best = -INFINITY;
    int   bidx = 0;
    #pragma unroll
    for (int p = 0; p < 4; ++p) {
        // non-temporal: x is read exactly once; don't evict ml from L2
        f4 v = __builtin_nontemporal_load(&rp[p * 64 + lane]);
        int base = (p * 64 + lane) * 4;
        // per-lane indices increase monotonically -> strict '>' keeps the
        // first occurrence (jnp.argmax tie-break)
        if (v.x > best) { best = v.x; bidx = base;     }
        if (v.y > best) { best = v.y; bidx = base + 1; }
        if (v.z > best) { best = v.z; bidx = base + 2; }
        if (v.w > best) { best = v.w; bidx = base + 3; }
    }
    #pragma unroll
    for (int off = 32; off > 0; off >>= 1) {
        float ov = __shfl_xor(best, off);
        int   oi = __shfl_xor(bidx, off);
        if (ov > best || (ov == best && oi < bidx)) { best = ov; bidx = oi; }
    }

    const int t = row >> 5;          // row / BATCH   (BATCH == 32)
    const int b = row & (BATCH - 1); // row % BATCH
    if (lane == 0) ml[b * T_LEN + t] = bidx;

    // ---------------- completion detection (release/acquire) ----------------
    int done = 0;
    if (lane == 0) {
        __threadfence();                                  // release ml write
        done = (atomicAdd(&counters[b], 1) == T_LEN - 1); // device-scope
    }
    done = __shfl(done, 0);
    if (!done) return;
    __threadfence();                                      // acquire all ml[b][*]

    // ---------------- Phase 2: compaction for batch b (one wave) ------------
    int len = lengths[b];
    if (len > T_LEN) len = T_LEN;
    if (len < 0)     len = 0;

    const int4* rowp = (const int4*)(ml + b * T_LEN);     // 500 int4
    int*        tok  = out + b * T_LEN;

    int offset = 0;      // running kept-symbol count
    int carry  = -1;     // last ml value of previous chunk

    #pragma unroll
    for (int c = 0; c < 8; ++c) {                         // 8 chunks of 256 t
        int i4 = c * 64 + lane;                           // int4 index
        int4 m = make_int4(BLANK, BLANK, BLANK, BLANK);
        if (i4 < T_LEN / 4) m = rowp[i4];
        int t0 = i4 * 4;

        int prev0 = __shfl_up(m.w, 1);                    // lane-1's last elem
        if (lane == 0) prev0 = carry;

        bool k0 = (t0     < len) && (m.x != BLANK) && (m.x != prev0);
        bool k1 = (t0 + 1 < len) && (m.y != BLANK) && (m.y != m.x);
        bool k2 = (t0 + 2 < len) && (m.z != BLANK) && (m.z != m.y);
        bool k3 = (t0 + 3 < len) && (m.w != BLANK) && (m.w != m.z);

        int cnt = (int)k0 + (int)k1 + (int)k2 + (int)k3;

        // inclusive wave scan of per-lane counts
        int inc = cnt;
        #pragma unroll
        for (int off = 1; off < 64; off <<= 1) {
            int v = __shfl_up(inc, off);
            if (lane >= off) inc += v;
        }

        int p = offset + inc - cnt;                       // exclusive base
        if (k0) tok[p++] = m.x;
        if (k1) tok[p++] = m.y;
        if (k2) tok[p++] = m.z;
        if (k3) tok[p++] = m.w;

        offset += __shfl(inc, 63);                        // chunk total
        carry   = __shfl(m.w, 63);
    }

    // tail fill with -1 (disjoint from the scatter above)
    for (int t2 = offset + lane; t2 < T_LEN; t2 += 64) tok[t2] = -1;

    if (lane == 0) out[BATCH * T_LEN + b] = offset;       // out_lengths
}

extern "C" void kernel_launch(void* const* d_in, const int* in_sizes, int n_in,
                              void* d_out, int out_size, void* d_ws, size_t ws_size,
                              hipStream_t stream) {
    const float* x       = (const float*)d_in[0];
    const int*   lengths = (const int*)d_in[1];
    int*         out     = (int*)d_out;

    // d_ws layout: [0,128)   per-batch completion counters (32 int)
    //              [128,...) ml, B*T int32 = 256000 B (16B-aligned at +128)
    int* counters = (int*)d_ws;
    int* ml       = (int*)((char*)d_ws + 128);

    hipMemsetAsync(counters, 0, BATCH * sizeof(int), stream);

    const int nrows = T_LEN * BATCH;                      // 64000 rows
    ctc_fused_kernel<<<nrows / 4, 256, 0, stream>>>(x, lengths, out, ml, counters);
}

// Round 3
// 45.444 us; speedup vs baseline: 45.9231x; 45.9231x over previous
//
#include <hip/hip_runtime.h>

#define T_LEN 2000
#define BATCH 32
#define ALPHA 1024
#define BLANK 0

typedef float f4 __attribute__((ext_vector_type(4)));

// Kernel 1: argmax over alphabet axis. One 64-lane wave per (t,b) row.
// x layout: [t][b][a] (row = t*BATCH + b, contiguous in a).
// Writes ml transposed to [b][t] for kernel 2's per-batch scan.
__global__ __launch_bounds__(256) void ctc_argmax_kernel(
    const float* __restrict__ x, int* __restrict__ ml)
{
    const int wave = threadIdx.x >> 6;
    const int lane = threadIdx.x & 63;
    const int row  = blockIdx.x * 4 + wave;      // row = t*BATCH + b

    const f4* rp = (const f4*)(x + (size_t)row * ALPHA);

    float best = -INFINITY;
    int   bidx = 0;
    #pragma unroll
    for (int p = 0; p < 4; ++p) {
        f4 v = rp[p * 64 + lane];                // coalesced: 1KB/wave/instr
        int base = (p * 64 + lane) * 4;
        // per-lane indices increase monotonically -> strict '>' keeps the
        // first occurrence (jnp.argmax tie-break)
        if (v.x > best) { best = v.x; bidx = base;     }
        if (v.y > best) { best = v.y; bidx = base + 1; }
        if (v.z > best) { best = v.z; bidx = base + 2; }
        if (v.w > best) { best = v.w; bidx = base + 3; }
    }

    // wave butterfly reduce: larger value wins; on tie, smaller index
    #pragma unroll
    for (int off = 32; off > 0; off >>= 1) {
        float ov = __shfl_xor(best, off);
        int   oi = __shfl_xor(bidx, off);
        if (ov > best || (ov == best && oi < bidx)) { best = ov; bidx = oi; }
    }

    if (lane == 0) {
        const int t = row >> 5;                  // row / BATCH  (BATCH == 32)
        const int b = row & (BATCH - 1);         // row % BATCH
        ml[b * T_LEN + t] = bidx;
    }
}

// Kernel 2: parallel CTC compaction. One 256-thread block per batch element.
// Each thread owns 8 consecutive t (2x int4); block-wide exclusive scan of
// per-thread keep-counts (wave shfl scan + LDS wave-total scan), then scatter.
__global__ __launch_bounds__(256) void ctc_compact_kernel(
    const int* __restrict__ ml, const int* __restrict__ lengths,
    int* __restrict__ out)
{
    const int b    = blockIdx.x;
    const int tid  = threadIdx.x;
    const int lane = tid & 63;
    const int wid  = tid >> 6;

    int len = lengths[b];
    if (len > T_LEN) len = T_LEN;
    if (len < 0)     len = 0;

    const int*  row  = ml + b * T_LEN;
    const int4* rowp = (const int4*)row;         // 500 int4 (T_LEN/4)
    int*        tok  = out + b * T_LEN;

    // load 8 elements (threads 250..255 have no data)
    const int t0   = tid * 8;
    const bool act = (t0 < T_LEN);
    int m[8];
    if (act) {
        int4 a = rowp[tid * 2];
        int4 c = rowp[tid * 2 + 1];
        m[0]=a.x; m[1]=a.y; m[2]=a.z; m[3]=a.w;
        m[4]=c.x; m[5]=c.y; m[6]=c.z; m[7]=c.w;
    } else {
        #pragma unroll
        for (int j = 0; j < 8; ++j) m[j] = BLANK;
    }
    int prev0 = (act && t0 > 0) ? row[t0 - 1] : -1;   // direct load, L2/L3-hot

    bool k[8];
    int  cnt = 0;
    #pragma unroll
    for (int j = 0; j < 8; ++j) {
        int pv = (j == 0) ? prev0 : m[j - 1];
        k[j] = (t0 + j < len) && (m[j] != BLANK) && (m[j] != pv);
        cnt += (int)k[j];
    }

    // wave-inclusive scan of cnt
    int inc = cnt;
    #pragma unroll
    for (int off = 1; off < 64; off <<= 1) {
        int v = __shfl_up(inc, off);
        if (lane >= off) inc += v;
    }

    __shared__ int wtot[4];
    __shared__ int wbase[5];
    if (lane == 63) wtot[wid] = inc;
    __syncthreads();
    if (tid == 0) {
        int s = 0;
        #pragma unroll
        for (int w = 0; w < 4; ++w) { wbase[w] = s; s += wtot[w]; }
        wbase[4] = s;
    }
    __syncthreads();

    int p     = wbase[wid] + inc - cnt;          // exclusive prefix
    int total = wbase[4];

    #pragma unroll
    for (int j = 0; j < 8; ++j)
        if (k[j]) tok[p++] = m[j];

    // tail fill with -1 (positions [total, T) — disjoint from scatter)
    for (int t = total + tid; t < T_LEN; t += 256) tok[t] = -1;

    if (tid == 0) out[BATCH * T_LEN + b] = total;     // out_lengths
}

extern "C" void kernel_launch(void* const* d_in, const int* in_sizes, int n_in,
                              void* d_out, int out_size, void* d_ws, size_t ws_size,
                              hipStream_t stream) {
    const float* x       = (const float*)d_in[0];
    const int*   lengths = (const int*)d_in[1];
    int*         out     = (int*)d_out;
    int*         ml      = (int*)d_ws;           // B*T int32 = 256 KB scratch

    const int nrows = T_LEN * BATCH;             // 64000 rows, grid exact
    ctc_argmax_kernel<<<nrows / 4, 256, 0, stream>>>(x, ml);
    ctc_compact_kernel<<<BATCH, 256, 0, stream>>>(ml, lengths, out);
}

// Round 4
// 44.729 us; speedup vs baseline: 46.6574x; 1.0160x over previous
//
#include <hip/hip_runtime.h>

#define T_LEN 2000
#define BATCH 32
#define ALPHA 1024
#define BLANK 0

typedef float f4 __attribute__((ext_vector_type(4)));

// Kernel 1: argmax over alphabet axis. One 64-lane wave per (t,b) row.
// x layout: [t][b][a] (row = t*BATCH + b, contiguous in a).
// Writes ml transposed to [b][t] for kernel 2's per-batch scan.
// x is read exactly once -> non-temporal loads (keep L2 for ml).
__global__ __launch_bounds__(256) void ctc_argmax_kernel(
    const float* __restrict__ x, int* __restrict__ ml)
{
    const int wave = threadIdx.x >> 6;
    const int lane = threadIdx.x & 63;
    const int row  = blockIdx.x * 4 + wave;      // row = t*BATCH + b

    const f4* rp = (const f4*)(x + (size_t)row * ALPHA);

    float best = -INFINITY;
    int   bidx = 0;
    #pragma unroll
    for (int p = 0; p < 4; ++p) {
        f4 v = __builtin_nontemporal_load(&rp[p * 64 + lane]);  // streaming read
        int base = (p * 64 + lane) * 4;
        // per-lane indices increase monotonically -> strict '>' keeps the
        // first occurrence (jnp.argmax tie-break)
        if (v.x > best) { best = v.x; bidx = base;     }
        if (v.y > best) { best = v.y; bidx = base + 1; }
        if (v.z > best) { best = v.z; bidx = base + 2; }
        if (v.w > best) { best = v.w; bidx = base + 3; }
    }

    // wave butterfly reduce: larger value wins; on tie, smaller index
    #pragma unroll
    for (int off = 32; off > 0; off >>= 1) {
        float ov = __shfl_xor(best, off);
        int   oi = __shfl_xor(bidx, off);
        if (ov > best || (ov == best && oi < bidx)) { best = ov; bidx = oi; }
    }

    if (lane == 0) {
        const int t = row >> 5;                  // row / BATCH  (BATCH == 32)
        const int b = row & (BATCH - 1);         // row % BATCH
        ml[b * T_LEN + t] = bidx;
    }
}

// Kernel 2: parallel CTC compaction. One 256-thread block per batch element.
// Each thread owns 8 consecutive t (2x int4); block-wide exclusive scan of
// per-thread keep-counts (wave shfl scan + LDS wave-total scan), then scatter.
__global__ __launch_bounds__(256) void ctc_compact_kernel(
    const int* __restrict__ ml, const int* __restrict__ lengths,
    int* __restrict__ out)
{
    const int b    = blockIdx.x;
    const int tid  = threadIdx.x;
    const int lane = tid & 63;
    const int wid  = tid >> 6;

    int len = lengths[b];
    if (len > T_LEN) len = T_LEN;
    if (len < 0)     len = 0;

    const int*  row  = ml + b * T_LEN;
    const int4* rowp = (const int4*)row;         // 500 int4 (T_LEN/4)
    int*        tok  = out + b * T_LEN;

    // load 8 elements (threads 250..255 have no data)
    const int t0   = tid * 8;
    const bool act = (t0 < T_LEN);
    int m[8];
    if (act) {
        int4 a = rowp[tid * 2];
        int4 c = rowp[tid * 2 + 1];
        m[0]=a.x; m[1]=a.y; m[2]=a.z; m[3]=a.w;
        m[4]=c.x; m[5]=c.y; m[6]=c.z; m[7]=c.w;
    } else {
        #pragma unroll
        for (int j = 0; j < 8; ++j) m[j] = BLANK;
    }
    int prev0 = (act && t0 > 0) ? row[t0 - 1] : -1;   // direct load, L2-hot

    bool k[8];
    int  cnt = 0;
    #pragma unroll
    for (int j = 0; j < 8; ++j) {
        int pv = (j == 0) ? prev0 : m[j - 1];
        k[j] = (t0 + j < len) && (m[j] != BLANK) && (m[j] != pv);
        cnt += (int)k[j];
    }

    // wave-inclusive scan of cnt
    int inc = cnt;
    #pragma unroll
    for (int off = 1; off < 64; off <<= 1) {
        int v = __shfl_up(inc, off);
        if (lane >= off) inc += v;
    }

    __shared__ int wtot[4];
    __shared__ int wbase[5];
    if (lane == 63) wtot[wid] = inc;
    __syncthreads();
    if (tid == 0) {
        int s = 0;
        #pragma unroll
        for (int w = 0; w < 4; ++w) { wbase[w] = s; s += wtot[w]; }
        wbase[4] = s;
    }
    __syncthreads();

    int p     = wbase[wid] + inc - cnt;          // exclusive prefix
    int total = wbase[4];

    #pragma unroll
    for (int j = 0; j < 8; ++j)
        if (k[j]) tok[p++] = m[j];

    // tail fill with -1 (positions [total, T) — disjoint from scatter)
    for (int t = total + tid; t < T_LEN; t += 256) tok[t] = -1;

    if (tid == 0) out[BATCH * T_LEN + b] = total;     // out_lengths
}

extern "C" void kernel_launch(void* const* d_in, const int* in_sizes, int n_in,
                              void* d_out, int out_size, void* d_ws, size_t ws_size,
                              hipStream_t stream) {
    const float* x       = (const float*)d_in[0];
    const int*   lengths = (const int*)d_in[1];
    int*         out     = (int*)d_out;
    int*         ml      = (int*)d_ws;           // B*T int32 = 256 KB scratch

    const int nrows = T_LEN * BATCH;             // 64000 rows, grid exact
    ctc_argmax_kernel<<<nrows / 4, 256, 0, stream>>>(x, ml);
    ctc_compact_kernel<<<BATCH, 256, 0, stream>>>(ml, lengths, out);
}